// Round 7
// baseline (11673.008 us; speedup 1.0000x reference)
//
#include <hip/hip_runtime.h>

typedef unsigned short u16;
typedef unsigned long long u64;
typedef _Float16 half8 __attribute__((ext_vector_type(8)));
typedef float f32x4 __attribute__((ext_vector_type(4)));
typedef int i32x4 __attribute__((ext_vector_type(4)));

#define SEQ 512
#define MB 32
#define HD 1024
#define ID 256
#define OD 256
#define MBHD (MB * HD)
#define NBLK 192

__device__ __forceinline__ u16 f16b(float v) {
  union { _Float16 h; u16 u; } cv;
  cv.h = (_Float16)v;
  return cv.u;
}
__device__ __forceinline__ u64 pk64(float a, float b) {
  union { float f[2]; u64 u; } c; c.f[0] = a; c.f[1] = b; return c.u;
}
__device__ __forceinline__ float2 upk64(u64 v) {
  union { u64 u; float2 f; } c; c.u = v; return c.f;
}
__device__ __forceinline__ unsigned pk16x2(float a, float b) {
  union { _Float16 h[2]; unsigned u; } c;
  c.h[0] = (_Float16)a; c.h[1] = (_Float16)b; return c.u;
}

// Device-scope coherent ops (sc1 = MALL point, cross-XCD safe; rounds 4-6 proven).
__device__ __forceinline__ void cst4(void* p, unsigned v) {
  asm volatile("global_store_dword %0, %1, off sc1" :: "v"(p), "v"(v) : "memory");
}
__device__ __forceinline__ void cst8(void* p, u64 v) {
  asm volatile("global_store_dwordx2 %0, %1, off sc1" :: "v"(p), "v"(v) : "memory");
}
__device__ __forceinline__ u64 cld8(const void* p) {
  u64 v;
  asm volatile("global_load_dwordx2 %0, %1, off sc1\n\ts_waitcnt vmcnt(0)"
               : "=&v"(v) : "v"(p) : "memory");
  return v;
}

struct GruP {
  const float *bh0, *bh1, *by;
  const u16 *X16, *WtA0, *WtB0, *WtC1, *WtD1, *WtY;
  u16 *h016, *h116;       // fp16 parity-2 [2][MBHD]
  u16 *rh016, *rh116;     // fp16 [MBHD]
  float *h0f32, *h1f32;   // fp32 parity-2 [2][MBHD]
  unsigned* bar;
  float* out;
};

// Flat all-poll grid barrier: block w sc1-stores epoch to bar[w]; every thread
// polls one slot; __syncthreads_and converges. No atomics, no sleep quantization.
__device__ __forceinline__ void gbar(unsigned* bar, int w, unsigned ep) {
  asm volatile("s_waitcnt vmcnt(0)" ::: "memory");
  __syncthreads();
  if (threadIdx.x == 0) cst4(&bar[w], ep + 1u);
  const unsigned* sp = bar + threadIdx.x;
  int ok = 0;
  for (int it = 0; it < (1 << 17) && !ok; ++it) {
    unsigned v;
    asm volatile("global_load_dword %0, %1, off sc1\n\ts_waitcnt vmcnt(0)"
                 : "=&v"(v) : "v"(sp) : "memory");
    ok = __syncthreads_and((int)(threadIdx.x >= NBLK || v > ep));
  }
  asm volatile("" ::: "memory");
}

// Stage X slice (chunks [0,32)) via cached 16B loads (read-only).
template <int K>
__device__ __forceinline__ void stage_x(u16* sm, const u16* __restrict__ xrow, int tid) {
#pragma unroll
  for (int it = 0; it < 4; ++it) {
    int i = it * 256 + tid;
    int r = i >> 5, c = i & 31;
    i32x4 v = *(const i32x4*)(xrow + (size_t)r * (SEQ * ID) + (c << 3));
    *(i32x4*)(sm + r * K + ((c ^ (r & 7)) << 3)) = v;
  }
}

#define LD16(OUT0, ADDR)                                         \
  "global_load_dwordx4 %" #OUT0 ", %" #ADDR ", off sc1\n\t"
#define LD16O(OUT0, ADDR, OFF)                                   \
  "global_load_dwordx4 %" #OUT0 ", %" #ADDR ", off offset:" #OFF " sc1\n\t"

// Stage one fp16 [32][1024] source into chunks [C0,C0+128): thread (row=tid>>3,
// c0=tid&7) loads 16 chunks at base + k*128B -> one address reg, 16 imm-offset
// loads, ONE vmcnt(0).
template <int K, int C0>
__device__ __forceinline__ void stage16(u16* sm, const u16* __restrict__ src, int tid) {
  const int row = tid >> 3, c0 = tid & 7;
  const u16* b = src + (size_t)row * HD + (c0 << 3);
  i32x4 vv[16];
  asm volatile(
      LD16(0, 16) LD16O(1, 16, 128) LD16O(2, 16, 256) LD16O(3, 16, 384)
      LD16O(4, 16, 512) LD16O(5, 16, 640) LD16O(6, 16, 768) LD16O(7, 16, 896)
      LD16O(8, 16, 1024) LD16O(9, 16, 1152) LD16O(10, 16, 1280) LD16O(11, 16, 1408)
      LD16O(12, 16, 1536) LD16O(13, 16, 1664) LD16O(14, 16, 1792) LD16O(15, 16, 1920)
      "s_waitcnt vmcnt(0)"
      : "=&v"(vv[0]), "=&v"(vv[1]), "=&v"(vv[2]), "=&v"(vv[3]),
        "=&v"(vv[4]), "=&v"(vv[5]), "=&v"(vv[6]), "=&v"(vv[7]),
        "=&v"(vv[8]), "=&v"(vv[9]), "=&v"(vv[10]), "=&v"(vv[11]),
        "=&v"(vv[12]), "=&v"(vv[13]), "=&v"(vv[14]), "=&v"(vv[15])
      : "v"(b)
      : "memory");
  const int base = row * K, sx = row & 7;
#pragma unroll
  for (int k = 0; k < 16; ++k) {
    int c = C0 + c0 + (k << 3);
    *(i32x4*)(sm + base + ((c ^ sx) << 3)) = vv[k];
  }
}

// stage16 + 2x8B hprev preload (issued first; completes at the shared wait).
template <int K, int C0>
__device__ __forceinline__ void stage16hp(u16* sm, const u16* __restrict__ src, int tid,
                                          const float* hpp, u64& h0v, u64& h1v) {
  const int row = tid >> 3, c0 = tid & 7;
  const u16* b = src + (size_t)row * HD + (c0 << 3);
  i32x4 vv[16];
  asm volatile(
      "global_load_dwordx2 %16, %19, off sc1\n\t"
      "global_load_dwordx2 %17, %19, off offset:64 sc1\n\t"
      LD16(0, 18) LD16O(1, 18, 128) LD16O(2, 18, 256) LD16O(3, 18, 384)
      LD16O(4, 18, 512) LD16O(5, 18, 640) LD16O(6, 18, 768) LD16O(7, 18, 896)
      LD16O(8, 18, 1024) LD16O(9, 18, 1152) LD16O(10, 18, 1280) LD16O(11, 18, 1408)
      LD16O(12, 18, 1536) LD16O(13, 18, 1664) LD16O(14, 18, 1792) LD16O(15, 18, 1920)
      "s_waitcnt vmcnt(0)"
      : "=&v"(vv[0]), "=&v"(vv[1]), "=&v"(vv[2]), "=&v"(vv[3]),
        "=&v"(vv[4]), "=&v"(vv[5]), "=&v"(vv[6]), "=&v"(vv[7]),
        "=&v"(vv[8]), "=&v"(vv[9]), "=&v"(vv[10]), "=&v"(vv[11]),
        "=&v"(vv[12]), "=&v"(vv[13]), "=&v"(vv[14]), "=&v"(vv[15]),
        "=&v"(h0v), "=&v"(h1v)
      : "v"(b), "v"(hpp)
      : "memory");
  const int base = row * K, sx = row & 7;
#pragma unroll
  for (int k = 0; k < 16; ++k) {
    int c = C0 + c0 + (k << 3);
    *(i32x4*)(sm + base + ((c ^ sx) << 3)) = vv[k];
  }
}

// Two-source staging (alpha L1): 32 loads in flight, one vmcnt(0), + hprev.
__device__ __forceinline__ void stage32hp(u16* sm, const u16* __restrict__ s1,
                                          const u16* __restrict__ s2, int tid,
                                          const float* hpp, u64& h0v, u64& h1v) {
  const int row = tid >> 3, c0 = tid & 7;
  const u16* b1 = s1 + (size_t)row * HD + (c0 << 3);
  const u16* b2 = s2 + (size_t)row * HD + (c0 << 3);
  i32x4 vv[32];
  asm volatile(
      "global_load_dwordx2 %32, %36, off sc1\n\t"
      "global_load_dwordx2 %33, %36, off offset:64 sc1\n\t"
      LD16(0, 34) LD16O(1, 34, 128) LD16O(2, 34, 256) LD16O(3, 34, 384)
      LD16O(4, 34, 512) LD16O(5, 34, 640) LD16O(6, 34, 768) LD16O(7, 34, 896)
      LD16O(8, 34, 1024) LD16O(9, 34, 1152) LD16O(10, 34, 1280) LD16O(11, 34, 1408)
      LD16O(12, 34, 1536) LD16O(13, 34, 1664) LD16O(14, 34, 1792) LD16O(15, 34, 1920)
      LD16(16, 35) LD16O(17, 35, 128) LD16O(18, 35, 256) LD16O(19, 35, 384)
      LD16O(20, 35, 512) LD16O(21, 35, 640) LD16O(22, 35, 768) LD16O(23, 35, 896)
      LD16O(24, 35, 1024) LD16O(25, 35, 1152) LD16O(26, 35, 1280) LD16O(27, 35, 1408)
      LD16O(28, 35, 1536) LD16O(29, 35, 1664) LD16O(30, 35, 1792) LD16O(31, 35, 1920)
      "s_waitcnt vmcnt(0)"
      : "=&v"(vv[0]), "=&v"(vv[1]), "=&v"(vv[2]), "=&v"(vv[3]),
        "=&v"(vv[4]), "=&v"(vv[5]), "=&v"(vv[6]), "=&v"(vv[7]),
        "=&v"(vv[8]), "=&v"(vv[9]), "=&v"(vv[10]), "=&v"(vv[11]),
        "=&v"(vv[12]), "=&v"(vv[13]), "=&v"(vv[14]), "=&v"(vv[15]),
        "=&v"(vv[16]), "=&v"(vv[17]), "=&v"(vv[18]), "=&v"(vv[19]),
        "=&v"(vv[20]), "=&v"(vv[21]), "=&v"(vv[22]), "=&v"(vv[23]),
        "=&v"(vv[24]), "=&v"(vv[25]), "=&v"(vv[26]), "=&v"(vv[27]),
        "=&v"(vv[28]), "=&v"(vv[29]), "=&v"(vv[30]), "=&v"(vv[31]),
        "=&v"(h0v), "=&v"(h1v)
      : "v"(b1), "v"(b2), "v"(hpp)
      : "memory");
  const int base = row * 2048, sx = row & 7;
#pragma unroll
  for (int k = 0; k < 16; ++k) {
    int c = c0 + (k << 3);
    *(i32x4*)(sm + base + ((c ^ sx) << 3)) = vv[k];
    *(i32x4*)(sm + base + (((128 + c) ^ sx) << 3)) = vv[16 + k];
  }
}

// One wave: [32 x 32] partial over its K-quarter (2 col-frags, dual acc chains).
template <int K>
__device__ __forceinline__ void mm32(const u16* sm, const u16* __restrict__ Wt, int n0,
                                     int wave, int lane,
                                     f32x4& o0, f32x4& o1, f32x4& o2, f32x4& o3) {
  constexpr int NST = K >> 7;
  int b = lane >> 4, rr = lane & 15, sw = rr & 7;
  const u16* w0 = Wt + (size_t)(n0 + rr) * K + (b << 3);
  const u16* w1 = w0 + 16 * K;
  const u16* ar0 = sm + rr * K;
  const u16* ar1 = sm + (16 + rr) * K;
  int kbeg = wave * (K >> 2);
  f32x4 a0 = {0.f, 0.f, 0.f, 0.f}, a1 = a0, a2 = a0, a3 = a0;
  f32x4 c0v = a0, c1v = a0, c2v = a0, c3v = a0;
#pragma unroll
  for (int s = 0; s < NST; s += 2) {
    {
      int k0 = kbeg + (s << 5);
      int ci = (k0 >> 3) + b;
      half8 A0 = *(const half8*)(ar0 + ((ci ^ sw) << 3));
      half8 A1 = *(const half8*)(ar1 + ((ci ^ sw) << 3));
      half8 B0 = *(const half8*)(w0 + k0);
      half8 B1 = *(const half8*)(w1 + k0);
      a0 = __builtin_amdgcn_mfma_f32_16x16x32_f16(A0, B0, a0, 0, 0, 0);
      a1 = __builtin_amdgcn_mfma_f32_16x16x32_f16(A1, B0, a1, 0, 0, 0);
      a2 = __builtin_amdgcn_mfma_f32_16x16x32_f16(A0, B1, a2, 0, 0, 0);
      a3 = __builtin_amdgcn_mfma_f32_16x16x32_f16(A1, B1, a3, 0, 0, 0);
    }
    {
      int k0 = kbeg + ((s + 1) << 5);
      int ci = (k0 >> 3) + b;
      half8 A0 = *(const half8*)(ar0 + ((ci ^ sw) << 3));
      half8 A1 = *(const half8*)(ar1 + ((ci ^ sw) << 3));
      half8 B0 = *(const half8*)(w0 + k0);
      half8 B1 = *(const half8*)(w1 + k0);
      c0v = __builtin_amdgcn_mfma_f32_16x16x32_f16(A0, B0, c0v, 0, 0, 0);
      c1v = __builtin_amdgcn_mfma_f32_16x16x32_f16(A1, B0, c1v, 0, 0, 0);
      c2v = __builtin_amdgcn_mfma_f32_16x16x32_f16(A0, B1, c2v, 0, 0, 0);
      c3v = __builtin_amdgcn_mfma_f32_16x16x32_f16(A1, B1, c3v, 0, 0, 0);
    }
  }
  o0 = a0 + c0v; o1 = a1 + c1v; o2 = a2 + c2v; o3 = a3 + c3v;
}

__device__ __forceinline__ void put_psum(float (*ps)[MB][33], int wave, int rb, int cc,
                                         f32x4 o0, f32x4 o1, f32x4 o2, f32x4 o3) {
#pragma unroll
  for (int i = 0; i < 4; ++i) {
    ps[wave][rb + i][cc] = o0[i];
    ps[wave][16 + rb + i][cc] = o1[i];
    ps[wave][rb + i][16 + cc] = o2[i];
    ps[wave][16 + rb + i][16 + cc] = o3[i];
  }
}
__device__ __forceinline__ void sum4(const float (*ps)[MB][33], int m, int j8,
                                     float& s0, float& s1, float& s2, float& s3) {
  s0 = s1 = s2 = s3 = 0.f;
#pragma unroll
  for (int q = 0; q < 4; ++q) {
    s0 += ps[q][m][j8];
    s1 += ps[q][m][j8 + 1];
    s2 += ps[q][m][16 + j8];
    s3 += ps[q][m][17 + j8];
  }
}

__global__ void __launch_bounds__(256, 1) gru_main(GruP p) {
  __shared__ __align__(16) u16 sm[MB * 2048];   // 128 KB staged input
  __shared__ float psum[4][MB][33];             // 16.9 KB padded partials
  const int w = blockIdx.x, tid = threadIdx.x;
  const int wave = tid >> 6, lane = tid & 63;
  const int m = tid >> 3, j8 = (tid & 7) << 1;
  const int cc = lane & 15, rb = (lane >> 4) << 2;

  for (int t = 0; t <= SEQ + 1; ++t) {
    float zc0 = 0.f, zc1 = 0.f, zc2 = 0.f, zc3 = 0.f;
    float2 hpA = {0.f, 0.f}, hpB = {0.f, 0.f};
    // ======== tick ALPHA: z,r gates (L0 step t | L1 step t-1) ========
    if (w < 64) {
      if (t < SEQ) {
        int n0 = w << 5;
        stage_x<1280>(sm, p.X16 + (size_t)t * ID, tid);
        int colb = (w < 32) ? n0 : (n0 - HD);
        const float* hpp = p.h0f32 + (size_t)((t + 1) & 1) * MBHD + m * HD + colb + j8;
        u64 h0v, h1v;
        stage16hp<1280, 32>(sm, p.h016 + (size_t)((t + 1) & 1) * MBHD, tid,
                            hpp, h0v, h1v);
        __syncthreads();
        f32x4 o0, o1, o2, o3;
        mm32<1280>(sm, p.WtA0, n0, wave, lane, o0, o1, o2, o3);
        put_psum(psum, wave, rb, cc, o0, o1, o2, o3);
        __syncthreads();
        float s0, s1, s2, s3;
        sum4(psum, m, j8, s0, s1, s2, s3);
        s0 += p.bh0[n0 + j8];      s1 += p.bh0[n0 + j8 + 1];
        s2 += p.bh0[n0 + 16 + j8]; s3 += p.bh0[n0 + 17 + j8];
        s0 = 1.f / (1.f + __expf(-s0)); s1 = 1.f / (1.f + __expf(-s1));
        s2 = 1.f / (1.f + __expf(-s2)); s3 = 1.f / (1.f + __expf(-s3));
        float2 hp0 = upk64(h0v), hp1 = upk64(h1v);
        if (w < 32) {
          zc0 = s0; zc1 = s1; zc2 = s2; zc3 = s3; hpA = hp0; hpB = hp1;
        } else {
          int jr = n0 - HD + j8;
          cst4(p.rh016 + m * HD + jr, pk16x2(s0 * hp0.x, s1 * hp0.y));
          cst4(p.rh016 + m * HD + jr + 16, pk16x2(s2 * hp1.x, s3 * hp1.y));
        }
      }
    } else if (w >= 128) {
      if (t >= 1 && t <= SEQ) {
        int n0 = (w - 128) << 5;
        int colb = (w < 160) ? n0 : (n0 - HD);
        const float* hpp = p.h1f32 + (size_t)(t & 1) * MBHD + m * HD + colb + j8;
        u64 h0v, h1v;
        stage32hp(sm, p.h016 + (size_t)((t - 1) & 1) * MBHD,
                  p.h116 + (size_t)(t & 1) * MBHD, tid, hpp, h0v, h1v);
        __syncthreads();
        f32x4 o0, o1, o2, o3;
        mm32<2048>(sm, p.WtC1, n0, wave, lane, o0, o1, o2, o3);
        put_psum(psum, wave, rb, cc, o0, o1, o2, o3);
        __syncthreads();
        float s0, s1, s2, s3;
        sum4(psum, m, j8, s0, s1, s2, s3);
        s0 += p.bh1[n0 + j8];      s1 += p.bh1[n0 + j8 + 1];
        s2 += p.bh1[n0 + 16 + j8]; s3 += p.bh1[n0 + 17 + j8];
        s0 = 1.f / (1.f + __expf(-s0)); s1 = 1.f / (1.f + __expf(-s1));
        s2 = 1.f / (1.f + __expf(-s2)); s3 = 1.f / (1.f + __expf(-s3));
        float2 hp0 = upk64(h0v), hp1 = upk64(h1v);
        if (w < 160) {
          zc0 = s0; zc1 = s1; zc2 = s2; zc3 = s3; hpA = hp0; hpB = hp1;
        } else {
          int jr = n0 - HD + j8;
          cst4(p.rh116 + m * HD + jr, pk16x2(s0 * hp0.x, s1 * hp0.y));
          cst4(p.rh116 + m * HD + jr + 16, pk16x2(s2 * hp1.x, s3 * hp1.y));
        }
      }
    }
    gbar(p.bar, w, 2u * t);
    // ======== tick BETA: g + h update (L0 t | L1 t-1), y(t-2) ========
    if (w < 32) {
      if (t < SEQ) {
        int n0 = w << 5;
        // X chunks [0,32) still valid in LDS from this block's alpha staging.
        stage16<1280, 32>(sm, p.rh016, tid);
        __syncthreads();
        f32x4 o0, o1, o2, o3;
        mm32<1280>(sm, p.WtB0, n0, wave, lane, o0, o1, o2, o3);
        put_psum(psum, wave, rb, cc, o0, o1, o2, o3);
        __syncthreads();
        float s0, s1, s2, s3;
        sum4(psum, m, j8, s0, s1, s2, s3);
        s0 += p.bh0[2 * HD + n0 + j8];      s1 += p.bh0[2 * HD + n0 + j8 + 1];
        s2 += p.bh0[2 * HD + n0 + 16 + j8]; s3 += p.bh0[2 * HD + n0 + 17 + j8];
        float g0 = tanhf(s0), g1 = tanhf(s1), g2 = tanhf(s2), g3 = tanhf(s3);
        float hn0 = zc0 * hpA.x + (1.f - zc0) * g0;
        float hn1 = zc1 * hpA.y + (1.f - zc1) * g1;
        float hn2 = zc2 * hpB.x + (1.f - zc2) * g2;
        float hn3 = zc3 * hpB.y + (1.f - zc3) * g3;
        size_t ob = (size_t)(t & 1) * MBHD + m * HD + n0 + j8;
        cst8(p.h0f32 + ob, pk64(hn0, hn1));
        cst8(p.h0f32 + ob + 16, pk64(hn2, hn3));
        cst4(p.h016 + ob, pk16x2(hn0, hn1));
        cst4(p.h016 + ob + 16, pk16x2(hn2, hn3));
      }
    } else if (w >= 64 && w < 72) {
      if (t >= 2) {
        int n0 = (w - 64) << 5;
        stage16<1024, 0>(sm, p.h116 + (size_t)(t & 1) * MBHD, tid);
        __syncthreads();
        f32x4 o0, o1, o2, o3;
        mm32<1024>(sm, p.WtY, n0, wave, lane, o0, o1, o2, o3);
        put_psum(psum, wave, rb, cc, o0, o1, o2, o3);
        __syncthreads();
        float s0, s1, s2, s3;
        sum4(psum, m, j8, s0, s1, s2, s3);
        s0 += p.by[n0 + j8];      s1 += p.by[n0 + j8 + 1];
        s2 += p.by[n0 + 16 + j8]; s3 += p.by[n0 + 17 + j8];
        size_t ob = ((size_t)m * SEQ + (t - 2)) * OD + n0 + j8;
        *(float2*)&p.out[ob] = make_float2(s0, s1);
        *(float2*)&p.out[ob + 16] = make_float2(s2, s3);
      }
    } else if (w >= 128 && w < 160) {
      if (t >= 1 && t <= SEQ) {
        int n0 = (w - 128) << 5;
        // h0(t-1) chunks [0,128) still valid in LDS from this block's alpha.
        stage16<2048, 128>(sm, p.rh116, tid);
        __syncthreads();
        f32x4 o0, o1, o2, o3;
        mm32<2048>(sm, p.WtD1, n0, wave, lane, o0, o1, o2, o3);
        put_psum(psum, wave, rb, cc, o0, o1, o2, o3);
        __syncthreads();
        float s0, s1, s2, s3;
        sum4(psum, m, j8, s0, s1, s2, s3);
        s0 += p.bh1[2 * HD + n0 + j8];      s1 += p.bh1[2 * HD + n0 + j8 + 1];
        s2 += p.bh1[2 * HD + n0 + 16 + j8]; s3 += p.bh1[2 * HD + n0 + 17 + j8];
        float g0 = tanhf(s0), g1 = tanhf(s1), g2 = tanhf(s2), g3 = tanhf(s3);
        float hn0 = zc0 * hpA.x + (1.f - zc0) * g0;
        float hn1 = zc1 * hpA.y + (1.f - zc1) * g1;
        float hn2 = zc2 * hpB.x + (1.f - zc2) * g2;
        float hn3 = zc3 * hpB.y + (1.f - zc3) * g3;
        size_t ob = (size_t)((t - 1) & 1) * MBHD + m * HD + n0 + j8;
        cst8(p.h1f32 + ob, pk64(hn0, hn1));
        cst8(p.h1f32 + ob + 16, pk64(hn2, hn3));
        cst4(p.h116 + ob, pk16x2(hn0, hn1));
        cst4(p.h116 + ob + 16, pk16x2(hn2, hn3));
      }
    }
    gbar(p.bar, w, 2u * t + 1u);
  }
  // Epilogue: final hidden states (both in parity buffer 1 after step 511).
  if (w < MB) {
    const float* h0f = p.h0f32 + MBHD;
    const float* h1f = p.h1f32 + MBHD;
#pragma unroll
    for (int it = 0; it < 4; ++it) {
      int i2 = (it * 256 + tid) * 2;  // 0..2046 step 2 over 2*HD
      float2 v = (i2 < HD) ? upk64(cld8(&h0f[w * HD + i2]))
                           : upk64(cld8(&h1f[w * HD + (i2 - HD)]));
      *(float2*)&p.out[(size_t)MB * SEQ * OD + (size_t)w * 2 * HD + i2] = v;
    }
  }
}

// ---------------- prologue kernels ----------------

__global__ void convx_k(const float* __restrict__ x, u16* __restrict__ X16) {
  size_t i = (size_t)blockIdx.x * 256 + threadIdx.x;
  const float4* s = (const float4*)x + i * 2;
  float4 a = s[0], b = s[1];
  u16 o[8];
  o[0] = f16b(a.x); o[1] = f16b(a.y); o[2] = f16b(a.z); o[3] = f16b(a.w);
  o[4] = f16b(b.x); o[5] = f16b(b.y); o[6] = f16b(b.z); o[7] = f16b(b.w);
  *(int4*)(X16 + i * 8) = *(const int4*)o;
}

__global__ void inith_k(const float* __restrict__ h0in,
                        float* h0f32, float* h1f32, u16* h016, u16* h116) {
  int idx = blockIdx.x * 256 + threadIdx.x;  // [b][l][h], 65536
  float v = h0in[idx];
  int b = idx >> 11, rem = idx & 2047;
  int l = rem >> 10, h = rem & 1023;
  int o = MBHD + b * HD + h;                 // parity buffer 1
  if (l == 0) { h0f32[o] = v; h016[o] = f16b(v); }
  else        { h1f32[o] = v; h116[o] = f16b(v); }
}

// Build [N][K] fp16 transposed weight blocks (K = concat Wx rows then Wh rows).
__global__ void wtrans_k(const float* __restrict__ Wx0, const float* __restrict__ Wh0,
                         const float* __restrict__ Wx1, const float* __restrict__ Wh1,
                         const float* __restrict__ Wy,
                         u16* A0, u16* B0, u16* C1, u16* D1, u16* Y) {
  __shared__ u16 tile[32][34];
  int mid = blockIdx.z;
  int K, N, k1, coloff, ld; const float *b1, *b2; u16* dst;
  if (mid == 0)      { K = 1280; N = 2048; k1 = ID; coloff = 0;    ld = 3072; b1 = Wx0; b2 = Wh0; dst = A0; }
  else if (mid == 1) { K = 1280; N = 1024; k1 = ID; coloff = 2048; ld = 3072; b1 = Wx0; b2 = Wh0; dst = B0; }
  else if (mid == 2) { K = 2048; N = 2048; k1 = HD; coloff = 0;    ld = 3072; b1 = Wx1; b2 = Wh1; dst = C1; }
  else if (mid == 3) { K = 2048; N = 1024; k1 = HD; coloff = 2048; ld = 3072; b1 = Wx1; b2 = Wh1; dst = D1; }
  else               { K = 1024; N = 256;  k1 = HD; coloff = 0;    ld = OD;   b1 = Wy;  b2 = Wy;  dst = Y;  }
  int k0 = blockIdx.x << 5, n0 = blockIdx.y << 5;
  if (k0 >= K || n0 >= N) return;
  int tx = threadIdx.x & 31, ty = threadIdx.x >> 5;
#pragma unroll
  for (int i = 0; i < 4; ++i) {
    int kk = (ty << 2) + i, k = k0 + kk;
    int col = coloff + n0 + tx;
    const float* src = (k < k1) ? (b1 + (size_t)k * ld + col)
                                : (b2 + (size_t)(k - k1) * ld + col);
    tile[kk][tx] = f16b(*src);
  }
  __syncthreads();
#pragma unroll
  for (int i = 0; i < 4; ++i) {
    int nn = (ty << 2) + i;
    dst[(size_t)(n0 + nn) * K + k0 + tx] = tile[tx][nn];
  }
}

// ---------------- host launch ----------------

extern "C" void kernel_launch(void* const* d_in, const int* in_sizes, int n_in,
                              void* d_out, int out_size, void* d_ws, size_t ws_size,
                              hipStream_t stream) {
  const float* x    = (const float*)d_in[0];
  const float* h0in = (const float*)d_in[1];
  const float* Wx0  = (const float*)d_in[2];
  const float* Wh0  = (const float*)d_in[3];
  const float* bh0  = (const float*)d_in[4];
  const float* Wx1  = (const float*)d_in[5];
  const float* Wh1  = (const float*)d_in[6];
  const float* bh1  = (const float*)d_in[7];
  const float* Wy   = (const float*)d_in[8];
  const float* by   = (const float*)d_in[9];

  char* ws = (char*)d_ws;
  size_t off = 0;
  auto alloc = [&](size_t bytes) {
    void* pp = ws + off;
    off += (bytes + 255) & ~(size_t)255;
    return pp;
  };
  u16* WtA0 = (u16*)alloc(2048ull * 1280 * 2);
  u16* WtB0 = (u16*)alloc(1024ull * 1280 * 2);
  u16* WtC1 = (u16*)alloc(2048ull * 2048 * 2);
  u16* WtD1 = (u16*)alloc(1024ull * 2048 * 2);
  u16* WtY  = (u16*)alloc(256ull * 1024 * 2);
  u16* X16  = (u16*)alloc((size_t)MB * SEQ * ID * 2);
  u16* h016  = (u16*)alloc(2ull * MBHD * 2);
  u16* h116  = (u16*)alloc(2ull * MBHD * 2);
  u16* rh016 = (u16*)alloc((size_t)MBHD * 2);
  u16* rh116 = (u16*)alloc((size_t)MBHD * 2);
  float* h0f32 = (float*)alloc(2ull * MBHD * 4);
  float* h1f32 = (float*)alloc(2ull * MBHD * 4);
  unsigned* bar = (unsigned*)alloc(8192);

  hipMemsetAsync(bar, 0, 8192, stream);
  hipLaunchKernelGGL(convx_k, dim3((MB * SEQ * ID / 8) / 256), dim3(256), 0, stream,
                     x, X16);
  hipLaunchKernelGGL(wtrans_k, dim3(64, 64, 5), dim3(256), 0, stream,
                     Wx0, Wh0, Wx1, Wh1, Wy, WtA0, WtB0, WtC1, WtD1, WtY);
  hipLaunchKernelGGL(inith_k, dim3(65536 / 256), dim3(256), 0, stream,
                     h0in, h0f32, h1f32, h016, h116);

  GruP p;
  p.bh0 = bh0; p.bh1 = bh1; p.by = by;
  p.X16 = X16; p.WtA0 = WtA0; p.WtB0 = WtB0; p.WtC1 = WtC1; p.WtD1 = WtD1; p.WtY = WtY;
  p.h016 = h016; p.h116 = h116; p.rh016 = rh016; p.rh116 = rh116;
  p.h0f32 = h0f32; p.h1f32 = h1f32;
  p.bar = bar;
  p.out = (float*)d_out;

  hipLaunchKernelGGL(gru_main, dim3(NBLK), dim3(256), 0, stream, p);
}

// Round 8
// 8555.480 us; speedup vs baseline: 1.3644x; 1.3644x over previous
//
#include <hip/hip_runtime.h>

typedef unsigned short u16;
typedef unsigned long long u64;
typedef _Float16 half8 __attribute__((ext_vector_type(8)));
typedef float f32x4 __attribute__((ext_vector_type(4)));
typedef int i32x4 __attribute__((ext_vector_type(4)));

#define SEQ 512
#define MB 32
#define HD 1024
#define ID 256
#define OD 256
#define MBHD (MB * HD)
#define NBLK 192
#define NGRP 12

__device__ __forceinline__ u16 f16b(float v) {
  union { _Float16 h; u16 u; } cv;
  cv.h = (_Float16)v;
  return cv.u;
}
__device__ __forceinline__ u64 pk64(float a, float b) {
  union { float f[2]; u64 u; } c; c.f[0] = a; c.f[1] = b; return c.u;
}
__device__ __forceinline__ float2 upk64(u64 v) {
  union { u64 u; float2 f; } c; c.u = v; return c.f;
}
__device__ __forceinline__ unsigned pk16x2(float a, float b) {
  union { _Float16 h[2]; unsigned u; } c;
  c.h[0] = (_Float16)a; c.h[1] = (_Float16)b; return c.u;
}

// Device-scope coherent ops (sc1 = MALL point, cross-XCD safe; rounds 4-7 proven).
__device__ __forceinline__ void cst4(void* p, unsigned v) {
  asm volatile("global_store_dword %0, %1, off sc1" :: "v"(p), "v"(v) : "memory");
}
__device__ __forceinline__ void cst8(void* p, u64 v) {
  asm volatile("global_store_dwordx2 %0, %1, off sc1" :: "v"(p), "v"(v) : "memory");
}
__device__ __forceinline__ u64 cld8(const void* p) {
  u64 v;
  asm volatile("global_load_dwordx2 %0, %1, off sc1\n\ts_waitcnt vmcnt(0)"
               : "=&v"(v) : "v"(p) : "memory");
  return v;
}

struct GruP {
  const float *bh0, *bh1, *by;
  const u16 *X16, *WtA0, *WtB0, *WtC1, *WtD1, *WtY;
  u16 *h016, *h116;       // fp16 parity-2 [2][MBHD]
  u16 *rh016, *rh116;     // fp16 [MBHD]
  float *h0f32, *h1f32;   // fp32 parity-2 [2][MBHD]
  unsigned* bar;
  float* out;
};

// Hierarchical grid barrier (round-4/5/6 proven at 256 blocks; adapted to 192 =
// 12 groups x 16). One thread per block: group-atomic -> root-atomic -> flag.
// Release = vmcnt(0): all prior device-scope stores complete at the MALL.
__device__ __forceinline__ void gbar(unsigned* bar, int w, unsigned ep) {
  asm volatile("s_waitcnt vmcnt(0)" ::: "memory");
  __syncthreads();
  if (threadIdx.x == 0) {
    unsigned old = __hip_atomic_fetch_add(&bar[(w >> 4) << 6], 1u,
                                          __ATOMIC_RELAXED, __HIP_MEMORY_SCOPE_AGENT);
    if (old == ep * 16u + 15u) {
      unsigned ro = __hip_atomic_fetch_add(&bar[1024], 1u,
                                           __ATOMIC_RELAXED, __HIP_MEMORY_SCOPE_AGENT);
      if (ro == ep * (unsigned)NGRP + (NGRP - 1u))
        __hip_atomic_store(&bar[1088], ep + 1u,
                           __ATOMIC_RELAXED, __HIP_MEMORY_SCOPE_AGENT);
    }
    for (int spin = 0; spin < (1 << 17); ++spin) {
      if (__hip_atomic_load(&bar[1088], __ATOMIC_RELAXED,
                            __HIP_MEMORY_SCOPE_AGENT) > ep)
        break;
      __builtin_amdgcn_s_sleep(1);
    }
  }
  __syncthreads();
  asm volatile("" ::: "memory");
}

// Stage X slice (chunks [0,32)) via cached 16B loads (read-only).
template <int K>
__device__ __forceinline__ void stage_x(u16* sm, const u16* __restrict__ xrow, int tid) {
#pragma unroll
  for (int it = 0; it < 4; ++it) {
    int i = it * 256 + tid;
    int r = i >> 5, c = i & 31;
    i32x4 v = *(const i32x4*)(xrow + (size_t)r * (SEQ * ID) + (c << 3));
    *(i32x4*)(sm + r * K + ((c ^ (r & 7)) << 3)) = v;
  }
}

#define LD16(OUT0, ADDR)                                         \
  "global_load_dwordx4 %" #OUT0 ", %" #ADDR ", off sc1\n\t"
#define LD16O(OUT0, ADDR, OFF)                                   \
  "global_load_dwordx4 %" #OUT0 ", %" #ADDR ", off offset:" #OFF " sc1\n\t"

// Stage one fp16 [32][1024] source into chunks [C0,C0+128): thread (row=tid>>3,
// c0=tid&7) loads 16 chunks at base + k*128B -> one address reg, 16 imm-offset
// loads, ONE vmcnt(0). (round-7 proven)
template <int K, int C0>
__device__ __forceinline__ void stage16(u16* sm, const u16* __restrict__ src, int tid) {
  const int row = tid >> 3, c0 = tid & 7;
  const u16* b = src + (size_t)row * HD + (c0 << 3);
  i32x4 vv[16];
  asm volatile(
      LD16(0, 16) LD16O(1, 16, 128) LD16O(2, 16, 256) LD16O(3, 16, 384)
      LD16O(4, 16, 512) LD16O(5, 16, 640) LD16O(6, 16, 768) LD16O(7, 16, 896)
      LD16O(8, 16, 1024) LD16O(9, 16, 1152) LD16O(10, 16, 1280) LD16O(11, 16, 1408)
      LD16O(12, 16, 1536) LD16O(13, 16, 1664) LD16O(14, 16, 1792) LD16O(15, 16, 1920)
      "s_waitcnt vmcnt(0)"
      : "=&v"(vv[0]), "=&v"(vv[1]), "=&v"(vv[2]), "=&v"(vv[3]),
        "=&v"(vv[4]), "=&v"(vv[5]), "=&v"(vv[6]), "=&v"(vv[7]),
        "=&v"(vv[8]), "=&v"(vv[9]), "=&v"(vv[10]), "=&v"(vv[11]),
        "=&v"(vv[12]), "=&v"(vv[13]), "=&v"(vv[14]), "=&v"(vv[15])
      : "v"(b)
      : "memory");
  const int base = row * K, sx = row & 7;
#pragma unroll
  for (int k = 0; k < 16; ++k) {
    int c = C0 + c0 + (k << 3);
    *(i32x4*)(sm + base + ((c ^ sx) << 3)) = vv[k];
  }
}

// stage16 + 2x8B hprev preload (issued first; completes at the shared wait).
template <int K, int C0>
__device__ __forceinline__ void stage16hp(u16* sm, const u16* __restrict__ src, int tid,
                                          const float* hpp, u64& h0v, u64& h1v) {
  const int row = tid >> 3, c0 = tid & 7;
  const u16* b = src + (size_t)row * HD + (c0 << 3);
  i32x4 vv[16];
  asm volatile(
      "global_load_dwordx2 %16, %19, off sc1\n\t"
      "global_load_dwordx2 %17, %19, off offset:64 sc1\n\t"
      LD16(0, 18) LD16O(1, 18, 128) LD16O(2, 18, 256) LD16O(3, 18, 384)
      LD16O(4, 18, 512) LD16O(5, 18, 640) LD16O(6, 18, 768) LD16O(7, 18, 896)
      LD16O(8, 18, 1024) LD16O(9, 18, 1152) LD16O(10, 18, 1280) LD16O(11, 18, 1408)
      LD16O(12, 18, 1536) LD16O(13, 18, 1664) LD16O(14, 18, 1792) LD16O(15, 18, 1920)
      "s_waitcnt vmcnt(0)"
      : "=&v"(vv[0]), "=&v"(vv[1]), "=&v"(vv[2]), "=&v"(vv[3]),
        "=&v"(vv[4]), "=&v"(vv[5]), "=&v"(vv[6]), "=&v"(vv[7]),
        "=&v"(vv[8]), "=&v"(vv[9]), "=&v"(vv[10]), "=&v"(vv[11]),
        "=&v"(vv[12]), "=&v"(vv[13]), "=&v"(vv[14]), "=&v"(vv[15]),
        "=&v"(h0v), "=&v"(h1v)
      : "v"(b), "v"(hpp)
      : "memory");
  const int base = row * K, sx = row & 7;
#pragma unroll
  for (int k = 0; k < 16; ++k) {
    int c = C0 + c0 + (k << 3);
    *(i32x4*)(sm + base + ((c ^ sx) << 3)) = vv[k];
  }
}

// Two-source staging (alpha L1): 32 loads in flight, one vmcnt(0), + hprev.
__device__ __forceinline__ void stage32hp(u16* sm, const u16* __restrict__ s1,
                                          const u16* __restrict__ s2, int tid,
                                          const float* hpp, u64& h0v, u64& h1v) {
  const int row = tid >> 3, c0 = tid & 7;
  const u16* b1 = s1 + (size_t)row * HD + (c0 << 3);
  const u16* b2 = s2 + (size_t)row * HD + (c0 << 3);
  i32x4 vv[32];
  asm volatile(
      "global_load_dwordx2 %32, %36, off sc1\n\t"
      "global_load_dwordx2 %33, %36, off offset:64 sc1\n\t"
      LD16(0, 34) LD16O(1, 34, 128) LD16O(2, 34, 256) LD16O(3, 34, 384)
      LD16O(4, 34, 512) LD16O(5, 34, 640) LD16O(6, 34, 768) LD16O(7, 34, 896)
      LD16O(8, 34, 1024) LD16O(9, 34, 1152) LD16O(10, 34, 1280) LD16O(11, 34, 1408)
      LD16O(12, 34, 1536) LD16O(13, 34, 1664) LD16O(14, 34, 1792) LD16O(15, 34, 1920)
      LD16(16, 35) LD16O(17, 35, 128) LD16O(18, 35, 256) LD16O(19, 35, 384)
      LD16O(20, 35, 512) LD16O(21, 35, 640) LD16O(22, 35, 768) LD16O(23, 35, 896)
      LD16O(24, 35, 1024) LD16O(25, 35, 1152) LD16O(26, 35, 1280) LD16O(27, 35, 1408)
      LD16O(28, 35, 1536) LD16O(29, 35, 1664) LD16O(30, 35, 1792) LD16O(31, 35, 1920)
      "s_waitcnt vmcnt(0)"
      : "=&v"(vv[0]), "=&v"(vv[1]), "=&v"(vv[2]), "=&v"(vv[3]),
        "=&v"(vv[4]), "=&v"(vv[5]), "=&v"(vv[6]), "=&v"(vv[7]),
        "=&v"(vv[8]), "=&v"(vv[9]), "=&v"(vv[10]), "=&v"(vv[11]),
        "=&v"(vv[12]), "=&v"(vv[13]), "=&v"(vv[14]), "=&v"(vv[15]),
        "=&v"(vv[16]), "=&v"(vv[17]), "=&v"(vv[18]), "=&v"(vv[19]),
        "=&v"(vv[20]), "=&v"(vv[21]), "=&v"(vv[22]), "=&v"(vv[23]),
        "=&v"(vv[24]), "=&v"(vv[25]), "=&v"(vv[26]), "=&v"(vv[27]),
        "=&v"(vv[28]), "=&v"(vv[29]), "=&v"(vv[30]), "=&v"(vv[31]),
        "=&v"(h0v), "=&v"(h1v)
      : "v"(b1), "v"(b2), "v"(hpp)
      : "memory");
  const int base = row * 2048, sx = row & 7;
#pragma unroll
  for (int k = 0; k < 16; ++k) {
    int c = c0 + (k << 3);
    *(i32x4*)(sm + base + ((c ^ sx) << 3)) = vv[k];
    *(i32x4*)(sm + base + (((128 + c) ^ sx) << 3)) = vv[16 + k];
  }
}

// One wave: [32 x 32] partial over its K-quarter (2 col-frags, dual acc chains).
template <int K>
__device__ __forceinline__ void mm32(const u16* sm, const u16* __restrict__ Wt, int n0,
                                     int wave, int lane,
                                     f32x4& o0, f32x4& o1, f32x4& o2, f32x4& o3) {
  constexpr int NST = K >> 7;
  int b = lane >> 4, rr = lane & 15, sw = rr & 7;
  const u16* w0 = Wt + (size_t)(n0 + rr) * K + (b << 3);
  const u16* w1 = w0 + 16 * K;
  const u16* ar0 = sm + rr * K;
  const u16* ar1 = sm + (16 + rr) * K;
  int kbeg = wave * (K >> 2);
  f32x4 a0 = {0.f, 0.f, 0.f, 0.f}, a1 = a0, a2 = a0, a3 = a0;
  f32x4 c0v = a0, c1v = a0, c2v = a0, c3v = a0;
#pragma unroll
  for (int s = 0; s < NST; s += 2) {
    {
      int k0 = kbeg + (s << 5);
      int ci = (k0 >> 3) + b;
      half8 A0 = *(const half8*)(ar0 + ((ci ^ sw) << 3));
      half8 A1 = *(const half8*)(ar1 + ((ci ^ sw) << 3));
      half8 B0 = *(const half8*)(w0 + k0);
      half8 B1 = *(const half8*)(w1 + k0);
      a0 = __builtin_amdgcn_mfma_f32_16x16x32_f16(A0, B0, a0, 0, 0, 0);
      a1 = __builtin_amdgcn_mfma_f32_16x16x32_f16(A1, B0, a1, 0, 0, 0);
      a2 = __builtin_amdgcn_mfma_f32_16x16x32_f16(A0, B1, a2, 0, 0, 0);
      a3 = __builtin_amdgcn_mfma_f32_16x16x32_f16(A1, B1, a3, 0, 0, 0);
    }
    {
      int k0 = kbeg + ((s + 1) << 5);
      int ci = (k0 >> 3) + b;
      half8 A0 = *(const half8*)(ar0 + ((ci ^ sw) << 3));
      half8 A1 = *(const half8*)(ar1 + ((ci ^ sw) << 3));
      half8 B0 = *(const half8*)(w0 + k0);
      half8 B1 = *(const half8*)(w1 + k0);
      c0v = __builtin_amdgcn_mfma_f32_16x16x32_f16(A0, B0, c0v, 0, 0, 0);
      c1v = __builtin_amdgcn_mfma_f32_16x16x32_f16(A1, B0, c1v, 0, 0, 0);
      c2v = __builtin_amdgcn_mfma_f32_16x16x32_f16(A0, B1, c2v, 0, 0, 0);
      c3v = __builtin_amdgcn_mfma_f32_16x16x32_f16(A1, B1, c3v, 0, 0, 0);
    }
  }
  o0 = a0 + c0v; o1 = a1 + c1v; o2 = a2 + c2v; o3 = a3 + c3v;
}

__device__ __forceinline__ void put_psum(float (*ps)[MB][33], int wave, int rb, int cc,
                                         f32x4 o0, f32x4 o1, f32x4 o2, f32x4 o3) {
#pragma unroll
  for (int i = 0; i < 4; ++i) {
    ps[wave][rb + i][cc] = o0[i];
    ps[wave][16 + rb + i][cc] = o1[i];
    ps[wave][rb + i][16 + cc] = o2[i];
    ps[wave][16 + rb + i][16 + cc] = o3[i];
  }
}
__device__ __forceinline__ void sum4(const float (*ps)[MB][33], int m, int j8,
                                     float& s0, float& s1, float& s2, float& s3) {
  s0 = s1 = s2 = s3 = 0.f;
#pragma unroll
  for (int q = 0; q < 4; ++q) {
    s0 += ps[q][m][j8];
    s1 += ps[q][m][j8 + 1];
    s2 += ps[q][m][16 + j8];
    s3 += ps[q][m][17 + j8];
  }
}

__global__ void __launch_bounds__(256, 1) gru_main(GruP p) {
  __shared__ __align__(16) u16 sm[MB * 2048];   // 128 KB staged input
  __shared__ float psum[4][MB][33];             // 16.9 KB padded partials
  const int w = blockIdx.x, tid = threadIdx.x;
  const int wave = tid >> 6, lane = tid & 63;
  const int m = tid >> 3, j8 = (tid & 7) << 1;
  const int cc = lane & 15, rb = (lane >> 4) << 2;

  for (int t = 0; t <= SEQ + 1; ++t) {
    float zc0 = 0.f, zc1 = 0.f, zc2 = 0.f, zc3 = 0.f;
    float2 hpA = {0.f, 0.f}, hpB = {0.f, 0.f};
    // ======== tick ALPHA: z,r gates (L0 step t | L1 step t-1) ========
    if (w < 64) {
      if (t < SEQ) {
        int n0 = w << 5;
        stage_x<1280>(sm, p.X16 + (size_t)t * ID, tid);
        int colb = (w < 32) ? n0 : (n0 - HD);
        const float* hpp = p.h0f32 + (size_t)((t + 1) & 1) * MBHD + m * HD + colb + j8;
        u64 h0v, h1v;
        stage16hp<1280, 32>(sm, p.h016 + (size_t)((t + 1) & 1) * MBHD, tid,
                            hpp, h0v, h1v);
        __syncthreads();
        f32x4 o0, o1, o2, o3;
        mm32<1280>(sm, p.WtA0, n0, wave, lane, o0, o1, o2, o3);
        put_psum(psum, wave, rb, cc, o0, o1, o2, o3);
        __syncthreads();
        float s0, s1, s2, s3;
        sum4(psum, m, j8, s0, s1, s2, s3);
        s0 += p.bh0[n0 + j8];      s1 += p.bh0[n0 + j8 + 1];
        s2 += p.bh0[n0 + 16 + j8]; s3 += p.bh0[n0 + 17 + j8];
        s0 = 1.f / (1.f + __expf(-s0)); s1 = 1.f / (1.f + __expf(-s1));
        s2 = 1.f / (1.f + __expf(-s2)); s3 = 1.f / (1.f + __expf(-s3));
        float2 hp0 = upk64(h0v), hp1 = upk64(h1v);
        if (w < 32) {
          zc0 = s0; zc1 = s1; zc2 = s2; zc3 = s3; hpA = hp0; hpB = hp1;
        } else {
          int jr = n0 - HD + j8;
          cst4(p.rh016 + m * HD + jr, pk16x2(s0 * hp0.x, s1 * hp0.y));
          cst4(p.rh016 + m * HD + jr + 16, pk16x2(s2 * hp1.x, s3 * hp1.y));
        }
      }
    } else if (w >= 128) {
      if (t >= 1 && t <= SEQ) {
        int n0 = (w - 128) << 5;
        int colb = (w < 160) ? n0 : (n0 - HD);
        const float* hpp = p.h1f32 + (size_t)(t & 1) * MBHD + m * HD + colb + j8;
        u64 h0v, h1v;
        stage32hp(sm, p.h016 + (size_t)((t - 1) & 1) * MBHD,
                  p.h116 + (size_t)(t & 1) * MBHD, tid, hpp, h0v, h1v);
        __syncthreads();
        f32x4 o0, o1, o2, o3;
        mm32<2048>(sm, p.WtC1, n0, wave, lane, o0, o1, o2, o3);
        put_psum(psum, wave, rb, cc, o0, o1, o2, o3);
        __syncthreads();
        float s0, s1, s2, s3;
        sum4(psum, m, j8, s0, s1, s2, s3);
        s0 += p.bh1[n0 + j8];      s1 += p.bh1[n0 + j8 + 1];
        s2 += p.bh1[n0 + 16 + j8]; s3 += p.bh1[n0 + 17 + j8];
        s0 = 1.f / (1.f + __expf(-s0)); s1 = 1.f / (1.f + __expf(-s1));
        s2 = 1.f / (1.f + __expf(-s2)); s3 = 1.f / (1.f + __expf(-s3));
        float2 hp0 = upk64(h0v), hp1 = upk64(h1v);
        if (w < 160) {
          zc0 = s0; zc1 = s1; zc2 = s2; zc3 = s3; hpA = hp0; hpB = hp1;
        } else {
          int jr = n0 - HD + j8;
          cst4(p.rh116 + m * HD + jr, pk16x2(s0 * hp0.x, s1 * hp0.y));
          cst4(p.rh116 + m * HD + jr + 16, pk16x2(s2 * hp1.x, s3 * hp1.y));
        }
      }
    }
    gbar(p.bar, w, 2u * t);
    // ======== tick BETA: g + h update (L0 t | L1 t-1), y(t-2) ========
    if (w < 32) {
      if (t < SEQ) {
        int n0 = w << 5;
        // X chunks [0,32) still valid in LDS from this block's alpha staging.
        stage16<1280, 32>(sm, p.rh016, tid);
        __syncthreads();
        f32x4 o0, o1, o2, o3;
        mm32<1280>(sm, p.WtB0, n0, wave, lane, o0, o1, o2, o3);
        put_psum(psum, wave, rb, cc, o0, o1, o2, o3);
        __syncthreads();
        float s0, s1, s2, s3;
        sum4(psum, m, j8, s0, s1, s2, s3);
        s0 += p.bh0[2 * HD + n0 + j8];      s1 += p.bh0[2 * HD + n0 + j8 + 1];
        s2 += p.bh0[2 * HD + n0 + 16 + j8]; s3 += p.bh0[2 * HD + n0 + 17 + j8];
        float g0 = tanhf(s0), g1 = tanhf(s1), g2 = tanhf(s2), g3 = tanhf(s3);
        float hn0 = zc0 * hpA.x + (1.f - zc0) * g0;
        float hn1 = zc1 * hpA.y + (1.f - zc1) * g1;
        float hn2 = zc2 * hpB.x + (1.f - zc2) * g2;
        float hn3 = zc3 * hpB.y + (1.f - zc3) * g3;
        size_t ob = (size_t)(t & 1) * MBHD + m * HD + n0 + j8;
        cst8(p.h0f32 + ob, pk64(hn0, hn1));
        cst8(p.h0f32 + ob + 16, pk64(hn2, hn3));
        cst4(p.h016 + ob, pk16x2(hn0, hn1));
        cst4(p.h016 + ob + 16, pk16x2(hn2, hn3));
      }
    } else if (w >= 64 && w < 72) {
      if (t >= 2) {
        int n0 = (w - 64) << 5;
        stage16<1024, 0>(sm, p.h116 + (size_t)(t & 1) * MBHD, tid);
        __syncthreads();
        f32x4 o0, o1, o2, o3;
        mm32<1024>(sm, p.WtY, n0, wave, lane, o0, o1, o2, o3);
        put_psum(psum, wave, rb, cc, o0, o1, o2, o3);
        __syncthreads();
        float s0, s1, s2, s3;
        sum4(psum, m, j8, s0, s1, s2, s3);
        s0 += p.by[n0 + j8];      s1 += p.by[n0 + j8 + 1];
        s2 += p.by[n0 + 16 + j8]; s3 += p.by[n0 + 17 + j8];
        size_t ob = ((size_t)m * SEQ + (t - 2)) * OD + n0 + j8;
        *(float2*)&p.out[ob] = make_float2(s0, s1);
        *(float2*)&p.out[ob + 16] = make_float2(s2, s3);
      }
    } else if (w >= 128 && w < 160) {
      if (t >= 1 && t <= SEQ) {
        int n0 = (w - 128) << 5;
        // h0(t-1) chunks [0,128) still valid in LDS from this block's alpha.
        stage16<2048, 128>(sm, p.rh116, tid);
        __syncthreads();
        f32x4 o0, o1, o2, o3;
        mm32<2048>(sm, p.WtD1, n0, wave, lane, o0, o1, o2, o3);
        put_psum(psum, wave, rb, cc, o0, o1, o2, o3);
        __syncthreads();
        float s0, s1, s2, s3;
        sum4(psum, m, j8, s0, s1, s2, s3);
        s0 += p.bh1[2 * HD + n0 + j8];      s1 += p.bh1[2 * HD + n0 + j8 + 1];
        s2 += p.bh1[2 * HD + n0 + 16 + j8]; s3 += p.bh1[2 * HD + n0 + 17 + j8];
        float g0 = tanhf(s0), g1 = tanhf(s1), g2 = tanhf(s2), g3 = tanhf(s3);
        float hn0 = zc0 * hpA.x + (1.f - zc0) * g0;
        float hn1 = zc1 * hpA.y + (1.f - zc1) * g1;
        float hn2 = zc2 * hpB.x + (1.f - zc2) * g2;
        float hn3 = zc3 * hpB.y + (1.f - zc3) * g3;
        size_t ob = (size_t)((t - 1) & 1) * MBHD + m * HD + n0 + j8;
        cst8(p.h1f32 + ob, pk64(hn0, hn1));
        cst8(p.h1f32 + ob + 16, pk64(hn2, hn3));
        cst4(p.h116 + ob, pk16x2(hn0, hn1));
        cst4(p.h116 + ob + 16, pk16x2(hn2, hn3));
      }
    }
    gbar(p.bar, w, 2u * t + 1u);
  }
  // Epilogue: final hidden states (both in parity buffer 1 after step 511).
  if (w < MB) {
    const float* h0f = p.h0f32 + MBHD;
    const float* h1f = p.h1f32 + MBHD;
#pragma unroll
    for (int it = 0; it < 4; ++it) {
      int i2 = (it * 256 + tid) * 2;  // 0..2046 step 2 over 2*HD
      float2 v = (i2 < HD) ? upk64(cld8(&h0f[w * HD + i2]))
                           : upk64(cld8(&h1f[w * HD + (i2 - HD)]));
      *(float2*)&p.out[(size_t)MB * SEQ * OD + (size_t)w * 2 * HD + i2] = v;
    }
  }
}

// ---------------- prologue kernels ----------------

__global__ void convx_k(const float* __restrict__ x, u16* __restrict__ X16) {
  size_t i = (size_t)blockIdx.x * 256 + threadIdx.x;
  const float4* s = (const float4*)x + i * 2;
  float4 a = s[0], b = s[1];
  u16 o[8];
  o[0] = f16b(a.x); o[1] = f16b(a.y); o[2] = f16b(a.z); o[3] = f16b(a.w);
  o[4] = f16b(b.x); o[5] = f16b(b.y); o[6] = f16b(b.z); o[7] = f16b(b.w);
  *(int4*)(X16 + i * 8) = *(const int4*)o;
}

__global__ void inith_k(const float* __restrict__ h0in,
                        float* h0f32, float* h1f32, u16* h016, u16* h116) {
  int idx = blockIdx.x * 256 + threadIdx.x;  // [b][l][h], 65536
  float v = h0in[idx];
  int b = idx >> 11, rem = idx & 2047;
  int l = rem >> 10, h = rem & 1023;
  int o = MBHD + b * HD + h;                 // parity buffer 1
  if (l == 0) { h0f32[o] = v; h016[o] = f16b(v); }
  else        { h1f32[o] = v; h116[o] = f16b(v); }
}

// Build [N][K] fp16 transposed weight blocks (K = concat Wx rows then Wh rows).
__global__ void wtrans_k(const float* __restrict__ Wx0, const float* __restrict__ Wh0,
                         const float* __restrict__ Wx1, const float* __restrict__ Wh1,
                         const float* __restrict__ Wy,
                         u16* A0, u16* B0, u16* C1, u16* D1, u16* Y) {
  __shared__ u16 tile[32][34];
  int mid = blockIdx.z;
  int K, N, k1, coloff, ld; const float *b1, *b2; u16* dst;
  if (mid == 0)      { K = 1280; N = 2048; k1 = ID; coloff = 0;    ld = 3072; b1 = Wx0; b2 = Wh0; dst = A0; }
  else if (mid == 1) { K = 1280; N = 1024; k1 = ID; coloff = 2048; ld = 3072; b1 = Wx0; b2 = Wh0; dst = B0; }
  else if (mid == 2) { K = 2048; N = 2048; k1 = HD; coloff = 0;    ld = 3072; b1 = Wx1; b2 = Wh1; dst = C1; }
  else if (mid == 3) { K = 2048; N = 1024; k1 = HD; coloff = 2048; ld = 3072; b1 = Wx1; b2 = Wh1; dst = D1; }
  else               { K = 1024; N = 256;  k1 = HD; coloff = 0;    ld = OD;   b1 = Wy;  b2 = Wy;  dst = Y;  }
  int k0 = blockIdx.x << 5, n0 = blockIdx.y << 5;
  if (k0 >= K || n0 >= N) return;
  int tx = threadIdx.x & 31, ty = threadIdx.x >> 5;
#pragma unroll
  for (int i = 0; i < 4; ++i) {
    int kk = (ty << 2) + i, k = k0 + kk;
    int col = coloff + n0 + tx;
    const float* src = (k < k1) ? (b1 + (size_t)k * ld + col)
                                : (b2 + (size_t)(k - k1) * ld + col);
    tile[kk][tx] = f16b(*src);
  }
  __syncthreads();
#pragma unroll
  for (int i = 0; i < 4; ++i) {
    int nn = (ty << 2) + i;
    dst[(size_t)(n0 + nn) * K + k0 + tx] = tile[tx][nn];
  }
}

// ---------------- host launch ----------------

extern "C" void kernel_launch(void* const* d_in, const int* in_sizes, int n_in,
                              void* d_out, int out_size, void* d_ws, size_t ws_size,
                              hipStream_t stream) {
  const float* x    = (const float*)d_in[0];
  const float* h0in = (const float*)d_in[1];
  const float* Wx0  = (const float*)d_in[2];
  const float* Wh0  = (const float*)d_in[3];
  const float* bh0  = (const float*)d_in[4];
  const float* Wx1  = (const float*)d_in[5];
  const float* Wh1  = (const float*)d_in[6];
  const float* bh1  = (const float*)d_in[7];
  const float* Wy   = (const float*)d_in[8];
  const float* by   = (const float*)d_in[9];

  char* ws = (char*)d_ws;
  size_t off = 0;
  auto alloc = [&](size_t bytes) {
    void* pp = ws + off;
    off += (bytes + 255) & ~(size_t)255;
    return pp;
  };
  u16* WtA0 = (u16*)alloc(2048ull * 1280 * 2);
  u16* WtB0 = (u16*)alloc(1024ull * 1280 * 2);
  u16* WtC1 = (u16*)alloc(2048ull * 2048 * 2);
  u16* WtD1 = (u16*)alloc(1024ull * 2048 * 2);
  u16* WtY  = (u16*)alloc(256ull * 1024 * 2);
  u16* X16  = (u16*)alloc((size_t)MB * SEQ * ID * 2);
  u16* h016  = (u16*)alloc(2ull * MBHD * 2);
  u16* h116  = (u16*)alloc(2ull * MBHD * 2);
  u16* rh016 = (u16*)alloc((size_t)MBHD * 2);
  u16* rh116 = (u16*)alloc((size_t)MBHD * 2);
  float* h0f32 = (float*)alloc(2ull * MBHD * 4);
  float* h1f32 = (float*)alloc(2ull * MBHD * 4);
  unsigned* bar = (unsigned*)alloc(8192);

  hipMemsetAsync(bar, 0, 8192, stream);
  hipLaunchKernelGGL(convx_k, dim3((MB * SEQ * ID / 8) / 256), dim3(256), 0, stream,
                     x, X16);
  hipLaunchKernelGGL(wtrans_k, dim3(64, 64, 5), dim3(256), 0, stream,
                     Wx0, Wh0, Wx1, Wh1, Wy, WtA0, WtB0, WtC1, WtD1, WtY);
  hipLaunchKernelGGL(inith_k, dim3(65536 / 256), dim3(256), 0, stream,
                     h0in, h0f32, h1f32, h016, h116);

  GruP p;
  p.bh0 = bh0; p.bh1 = bh1; p.by = by;
  p.X16 = X16; p.WtA0 = WtA0; p.WtB0 = WtB0; p.WtC1 = WtC1; p.WtD1 = WtD1; p.WtY = WtY;
  p.h016 = h016; p.h116 = h116; p.rh016 = rh016; p.rh116 = rh116;
  p.h0f32 = h0f32; p.h1f32 = h1f32;
  p.bar = bar;
  p.out = (float*)d_out;

  hipLaunchKernelGGL(gru_main, dim3(NBLK), dim3(256), 0, stream, p);
}

// Round 9
// 4463.328 us; speedup vs baseline: 2.6153x; 1.9168x over previous
//
#include <hip/hip_runtime.h>

typedef unsigned short u16;
typedef unsigned long long u64;
typedef _Float16 half8 __attribute__((ext_vector_type(8)));
typedef float f32x4 __attribute__((ext_vector_type(4)));
typedef int i32x4 __attribute__((ext_vector_type(4)));

#define SEQ 512
#define MB 32
#define HD 1024
#define ID 256
#define OD 256
#define MBHD (MB * HD)
#define NBLK 256

__device__ __forceinline__ u16 f16b(float v) {
  union { _Float16 h; u16 u; } cv;
  cv.h = (_Float16)v;
  return cv.u;
}
__device__ __forceinline__ u64 pk64(float a, float b) {
  union { float f[2]; u64 u; } c; c.f[0] = a; c.f[1] = b; return c.u;
}
__device__ __forceinline__ float2 upk64(u64 v) {
  union { u64 u; float2 f; } c; c.u = v; return c.f;
}
__device__ __forceinline__ unsigned pk16x2(float a, float b) {
  union { _Float16 h[2]; unsigned u; } c;
  c.h[0] = (_Float16)a; c.h[1] = (_Float16)b; return c.u;
}

// Device-scope coherent ops (sc1 = MALL point, cross-XCD safe; rounds 4-8 proven).
__device__ __forceinline__ void cst4(void* p, unsigned v) {
  asm volatile("global_store_dword %0, %1, off sc1" :: "v"(p), "v"(v) : "memory");
}
__device__ __forceinline__ void cst8(void* p, u64 v) {
  asm volatile("global_store_dwordx2 %0, %1, off sc1" :: "v"(p), "v"(v) : "memory");
}
__device__ __forceinline__ u64 cld8(const void* p) {
  u64 v;
  asm volatile("global_load_dwordx2 %0, %1, off sc1\n\ts_waitcnt vmcnt(0)"
               : "=&v"(v) : "v"(p) : "memory");
  return v;
}

struct GruP {
  const float *bh0, *bh1, *by;
  const u16 *X16, *WtA0, *WtB0, *WtC1, *WtD1, *WtY;
  u16 *h016, *h116;       // fp16 parity-2 [2][MBHD]
  u16 *rh016, *rh116;     // fp16 [MBHD]
  float *h0f32, *h1f32;   // fp32 parity-2 [2][MBHD]
  unsigned* bar;
  float* out;
};

// Hierarchical grid barrier (rounds 4-6 proven at 256 blocks): 16 groups of 16
// -> root -> epoch flag. Release = vmcnt(0) (device-scope stores at MALL).
__device__ __forceinline__ void gbar(unsigned* bar, int w, unsigned ep) {
  asm volatile("s_waitcnt vmcnt(0)" ::: "memory");
  __syncthreads();
  if (threadIdx.x == 0) {
    unsigned tgt = ep * 16u + 15u;
    unsigned old = __hip_atomic_fetch_add(&bar[(w >> 4) << 6], 1u,
                                          __ATOMIC_RELAXED, __HIP_MEMORY_SCOPE_AGENT);
    if (old == tgt) {
      unsigned ro = __hip_atomic_fetch_add(&bar[1024], 1u,
                                           __ATOMIC_RELAXED, __HIP_MEMORY_SCOPE_AGENT);
      if (ro == tgt)
        __hip_atomic_store(&bar[1088], ep + 1u,
                           __ATOMIC_RELAXED, __HIP_MEMORY_SCOPE_AGENT);
    }
    for (int spin = 0; spin < (1 << 17); ++spin) {
      if (__hip_atomic_load(&bar[1088], __ATOMIC_RELAXED,
                            __HIP_MEMORY_SCOPE_AGENT) > ep)
        break;
      __builtin_amdgcn_s_sleep(1);
    }
  }
  __syncthreads();
  asm volatile("" ::: "memory");
}

// Stage X slice (chunks [0,32)) via cached 16B loads (read-only, per-t fresh).
template <int K>
__device__ __forceinline__ void stage_x(u16* sm, const u16* __restrict__ xrow, int tid) {
#pragma unroll
  for (int it = 0; it < 4; ++it) {
    int i = it * 256 + tid;
    int r = i >> 5, c = i & 31;
    i32x4 v = *(const i32x4*)(xrow + (size_t)r * (SEQ * ID) + (c << 3));
    *(i32x4*)(sm + r * K + ((c ^ (r & 7)) << 3)) = v;
  }
}

#define LD16(OUT0, ADDR)                                         \
  "global_load_dwordx4 %" #OUT0 ", %" #ADDR ", off sc1\n\t"
#define LD16O(OUT0, ADDR, OFF)                                   \
  "global_load_dwordx4 %" #OUT0 ", %" #ADDR ", off offset:" #OFF " sc1\n\t"

// Stage one fp16 [32][1024] source into chunks [C0,C0+128): one address reg,
// 16 imm-offset 16B loads, ONE vmcnt(0). (r7/r8 proven)
template <int K, int C0>
__device__ __forceinline__ void stage16(u16* sm, const u16* __restrict__ src, int tid) {
  const int row = tid >> 3, c0 = tid & 7;
  const u16* b = src + (size_t)row * HD + (c0 << 3);
  i32x4 vv[16];
  asm volatile(
      LD16(0, 16) LD16O(1, 16, 128) LD16O(2, 16, 256) LD16O(3, 16, 384)
      LD16O(4, 16, 512) LD16O(5, 16, 640) LD16O(6, 16, 768) LD16O(7, 16, 896)
      LD16O(8, 16, 1024) LD16O(9, 16, 1152) LD16O(10, 16, 1280) LD16O(11, 16, 1408)
      LD16O(12, 16, 1536) LD16O(13, 16, 1664) LD16O(14, 16, 1792) LD16O(15, 16, 1920)
      "s_waitcnt vmcnt(0)"
      : "=&v"(vv[0]), "=&v"(vv[1]), "=&v"(vv[2]), "=&v"(vv[3]),
        "=&v"(vv[4]), "=&v"(vv[5]), "=&v"(vv[6]), "=&v"(vv[7]),
        "=&v"(vv[8]), "=&v"(vv[9]), "=&v"(vv[10]), "=&v"(vv[11]),
        "=&v"(vv[12]), "=&v"(vv[13]), "=&v"(vv[14]), "=&v"(vv[15])
      : "v"(b)
      : "memory");
  const int base = row * K, sx = row & 7;
#pragma unroll
  for (int k = 0; k < 16; ++k) {
    int c = C0 + c0 + (k << 3);
    *(i32x4*)(sm + base + ((c ^ sx) << 3)) = vv[k];
  }
}

// stage16 + 8B hprev preload (issued first; completes at the shared wait).
template <int K, int C0>
__device__ __forceinline__ void stage16hp(u16* sm, const u16* __restrict__ src, int tid,
                                          const void* hpp, u64& hpv) {
  const int row = tid >> 3, c0 = tid & 7;
  const u16* b = src + (size_t)row * HD + (c0 << 3);
  i32x4 vv[16];
  asm volatile(
      "global_load_dwordx2 %16, %18, off sc1\n\t"
      LD16(0, 17) LD16O(1, 17, 128) LD16O(2, 17, 256) LD16O(3, 17, 384)
      LD16O(4, 17, 512) LD16O(5, 17, 640) LD16O(6, 17, 768) LD16O(7, 17, 896)
      LD16O(8, 17, 1024) LD16O(9, 17, 1152) LD16O(10, 17, 1280) LD16O(11, 17, 1408)
      LD16O(12, 17, 1536) LD16O(13, 17, 1664) LD16O(14, 17, 1792) LD16O(15, 17, 1920)
      "s_waitcnt vmcnt(0)"
      : "=&v"(vv[0]), "=&v"(vv[1]), "=&v"(vv[2]), "=&v"(vv[3]),
        "=&v"(vv[4]), "=&v"(vv[5]), "=&v"(vv[6]), "=&v"(vv[7]),
        "=&v"(vv[8]), "=&v"(vv[9]), "=&v"(vv[10]), "=&v"(vv[11]),
        "=&v"(vv[12]), "=&v"(vv[13]), "=&v"(vv[14]), "=&v"(vv[15]),
        "=&v"(hpv)
      : "v"(b), "v"(hpp)
      : "memory");
  const int base = row * K, sx = row & 7;
#pragma unroll
  for (int k = 0; k < 16; ++k) {
    int c = C0 + c0 + (k << 3);
    *(i32x4*)(sm + base + ((c ^ sx) << 3)) = vv[k];
  }
}

// Two-source staging (alpha L1): 32 loads + hprev in flight, one vmcnt(0).
__device__ __forceinline__ void stage32hp(u16* sm, const u16* __restrict__ s1,
                                          const u16* __restrict__ s2, int tid,
                                          const void* hpp, u64& hpv) {
  const int row = tid >> 3, c0 = tid & 7;
  const u16* b1 = s1 + (size_t)row * HD + (c0 << 3);
  const u16* b2 = s2 + (size_t)row * HD + (c0 << 3);
  i32x4 vv[32];
  asm volatile(
      "global_load_dwordx2 %32, %35, off sc1\n\t"
      LD16(0, 33) LD16O(1, 33, 128) LD16O(2, 33, 256) LD16O(3, 33, 384)
      LD16O(4, 33, 512) LD16O(5, 33, 640) LD16O(6, 33, 768) LD16O(7, 33, 896)
      LD16O(8, 33, 1024) LD16O(9, 33, 1152) LD16O(10, 33, 1280) LD16O(11, 33, 1408)
      LD16O(12, 33, 1536) LD16O(13, 33, 1664) LD16O(14, 33, 1792) LD16O(15, 33, 1920)
      LD16(16, 34) LD16O(17, 34, 128) LD16O(18, 34, 256) LD16O(19, 34, 384)
      LD16O(20, 34, 512) LD16O(21, 34, 640) LD16O(22, 34, 768) LD16O(23, 34, 896)
      LD16O(24, 34, 1024) LD16O(25, 34, 1152) LD16O(26, 34, 1280) LD16O(27, 34, 1408)
      LD16O(28, 34, 1536) LD16O(29, 34, 1664) LD16O(30, 34, 1792) LD16O(31, 34, 1920)
      "s_waitcnt vmcnt(0)"
      : "=&v"(vv[0]), "=&v"(vv[1]), "=&v"(vv[2]), "=&v"(vv[3]),
        "=&v"(vv[4]), "=&v"(vv[5]), "=&v"(vv[6]), "=&v"(vv[7]),
        "=&v"(vv[8]), "=&v"(vv[9]), "=&v"(vv[10]), "=&v"(vv[11]),
        "=&v"(vv[12]), "=&v"(vv[13]), "=&v"(vv[14]), "=&v"(vv[15]),
        "=&v"(vv[16]), "=&v"(vv[17]), "=&v"(vv[18]), "=&v"(vv[19]),
        "=&v"(vv[20]), "=&v"(vv[21]), "=&v"(vv[22]), "=&v"(vv[23]),
        "=&v"(vv[24]), "=&v"(vv[25]), "=&v"(vv[26]), "=&v"(vv[27]),
        "=&v"(vv[28]), "=&v"(vv[29]), "=&v"(vv[30]), "=&v"(vv[31]),
        "=&v"(hpv)
      : "v"(b1), "v"(b2), "v"(hpp)
      : "memory");
  const int base = row * 2048, sx = row & 7;
#pragma unroll
  for (int k = 0; k < 16; ++k) {
    int c = c0 + (k << 3);
    *(i32x4*)(sm + base + ((c ^ sx) << 3)) = vv[k];
    *(i32x4*)(sm + base + (((128 + c) ^ sx) << 3)) = vv[16 + k];
  }
}

// Preload this block's weight slice into registers (static across the t-loop).
// Addressing identical to the old per-tick weight reads.
template <int K>
__device__ __forceinline__ void wload(half8* wr, const u16* __restrict__ Wt, int n0,
                                      int wave, int lane) {
  constexpr int NST = K >> 7;
  int b = lane >> 4, rr = lane & 15;
  const u16* base = Wt + (size_t)(n0 + rr) * K + wave * (K >> 2) + (b << 3);
#pragma unroll
  for (int s = 0; s < NST; ++s) wr[s] = *(const half8*)(base + (s << 5));
}

// One wave: partial [32 x 16] over its K-quarter. B-operand from REGISTERS.
// Dual accumulator chains. All array indices compile-time (full unroll).
template <int K>
__device__ __forceinline__ void mm16r(const u16* sm, const half8 (&wr)[16],
                                      int wave, int lane, f32x4& o0, f32x4& o1) {
  constexpr int NST = K >> 7;
  int b = lane >> 4, rr = lane & 15, sw = rr & 7;
  const u16* ar0 = sm + rr * K;
  const u16* ar1 = sm + (16 + rr) * K;
  int kbeg = wave * (K >> 2);
  f32x4 a0 = {0.f, 0.f, 0.f, 0.f}, a1 = a0, c0 = a0, c1 = a0;
#pragma unroll
  for (int s = 0; s < NST; s += 2) {
    {
      int ci = ((kbeg + (s << 5)) >> 3) + b;
      half8 A0 = *(const half8*)(ar0 + ((ci ^ sw) << 3));
      half8 A1 = *(const half8*)(ar1 + ((ci ^ sw) << 3));
      a0 = __builtin_amdgcn_mfma_f32_16x16x32_f16(A0, wr[s], a0, 0, 0, 0);
      a1 = __builtin_amdgcn_mfma_f32_16x16x32_f16(A1, wr[s], a1, 0, 0, 0);
    }
    {
      int ci = ((kbeg + ((s + 1) << 5)) >> 3) + b;
      half8 A0 = *(const half8*)(ar0 + ((ci ^ sw) << 3));
      half8 A1 = *(const half8*)(ar1 + ((ci ^ sw) << 3));
      c0 = __builtin_amdgcn_mfma_f32_16x16x32_f16(A0, wr[s + 1], c0, 0, 0, 0);
      c1 = __builtin_amdgcn_mfma_f32_16x16x32_f16(A1, wr[s + 1], c1, 0, 0, 0);
    }
  }
  o0 = a0 + c0;
  o1 = a1 + c1;
}

__global__ void __launch_bounds__(256, 1) gru_main(GruP p) {
  __shared__ __align__(16) u16 sm[MB * 2048];  // 128 KB staged input
  __shared__ float psum[4][MB][17];            // padded partials (bank-conflict fix)
  const int w = blockIdx.x, tid = threadIdx.x;
  const int wave = tid >> 6, lane = tid & 63;
  const int m = tid >> 3, jc = (tid & 7) << 1;
  const int cc = lane & 15, rb = (lane >> 4) << 2;

  // ---- one-time register preload of this block's weight slices ----
  half8 wP[16], wQ[16];
  if (w < 128) {
    wload<1280>(wP, p.WtA0, w << 4, wave, lane);
    if (w < 64)       wload<1280>(wQ, p.WtB0, w << 4, wave, lane);
    else if (w < 80)  wload<1024>(wQ, p.WtY, (w - 64) << 4, wave, lane);
  } else {
    wload<2048>(wP, p.WtC1, (w - 128) << 4, wave, lane);
    if (w < 192)      wload<2048>(wQ, p.WtD1, (w - 128) << 4, wave, lane);
  }

  for (int t = 0; t <= SEQ + 1; ++t) {
    float zc0 = 0.f, zc1 = 0.f;   // z-gate register carry (alpha -> beta)
    float2 hpc = {0.f, 0.f};      // hprev register carry (alpha -> beta)
    // ============ tick ALPHA: z,r gates (L0 step t | L1 step t-1) ============
    if (w < 128) {
      if (t < SEQ) {
        int n0 = w << 4;
        int j0 = n0 + jc;
        const float* hprev = p.h0f32 + (size_t)((t + 1) & 1) * MBHD;
        int pidx = m * HD + ((w < 64) ? j0 : (j0 - HD));
        stage_x<1280>(sm, p.X16 + (size_t)t * ID, tid);
        u64 hpv;
        stage16hp<1280, 32>(sm, p.h016 + (size_t)((t + 1) & 1) * MBHD, tid,
                            &hprev[pidx], hpv);
        __syncthreads();
        f32x4 a0, a1;
        mm16r<1280>(sm, wP, wave, lane, a0, a1);
#pragma unroll
        for (int i = 0; i < 4; ++i) {
          psum[wave][rb + i][cc] = a0[i];
          psum[wave][16 + rb + i][cc] = a1[i];
        }
        __syncthreads();
        float2 s0 = *(const float2*)&psum[0][m][jc];
        float2 s1v = *(const float2*)&psum[1][m][jc];
        float2 s2v = *(const float2*)&psum[2][m][jc];
        float2 s3v = *(const float2*)&psum[3][m][jc];
        float v0 = s0.x + s1v.x + s2v.x + s3v.x + p.bh0[j0];
        float v1 = s0.y + s1v.y + s2v.y + s3v.y + p.bh0[j0 + 1];
        v0 = 1.f / (1.f + __expf(-v0));
        v1 = 1.f / (1.f + __expf(-v1));
        float2 hp = upk64(hpv);
        if (w < 64) {
          zc0 = v0; zc1 = v1; hpc = hp;            // carry to beta in registers
        } else {
          cst4(p.rh016 + pidx, pk16x2(v0 * hp.x, v1 * hp.y));
        }
      }
    } else {
      if (t >= 1 && t <= SEQ) {
        int n0 = (w - 128) << 4;
        int j0 = n0 + jc;
        const float* hprev = p.h1f32 + (size_t)(t & 1) * MBHD;
        int pidx = m * HD + ((w < 192) ? j0 : (j0 - HD));
        u64 hpv;
        stage32hp(sm, p.h016 + (size_t)((t - 1) & 1) * MBHD,
                  p.h116 + (size_t)(t & 1) * MBHD, tid, &hprev[pidx], hpv);
        __syncthreads();
        f32x4 a0, a1;
        mm16r<2048>(sm, wP, wave, lane, a0, a1);
#pragma unroll
        for (int i = 0; i < 4; ++i) {
          psum[wave][rb + i][cc] = a0[i];
          psum[wave][16 + rb + i][cc] = a1[i];
        }
        __syncthreads();
        float2 s0 = *(const float2*)&psum[0][m][jc];
        float2 s1v = *(const float2*)&psum[1][m][jc];
        float2 s2v = *(const float2*)&psum[2][m][jc];
        float2 s3v = *(const float2*)&psum[3][m][jc];
        float v0 = s0.x + s1v.x + s2v.x + s3v.x + p.bh1[j0];
        float v1 = s0.y + s1v.y + s2v.y + s3v.y + p.bh1[j0 + 1];
        v0 = 1.f / (1.f + __expf(-v0));
        v1 = 1.f / (1.f + __expf(-v1));
        float2 hp = upk64(hpv);
        if (w < 192) {
          zc0 = v0; zc1 = v1; hpc = hp;            // carry to beta in registers
        } else {
          cst4(p.rh116 + pidx, pk16x2(v0 * hp.x, v1 * hp.y));
        }
      }
    }
    gbar(p.bar, w, 2u * t);
    // ============ tick BETA: g + h update (L0 t | L1 t-1), y(t-2) ============
    if (w < 64) {
      if (t < SEQ) {
        int j0 = (w << 4) + jc;
        // X chunks [0,32) persist in LDS from this block's alpha staging.
        stage16<1280, 32>(sm, p.rh016, tid);
        __syncthreads();
        f32x4 a0, a1;
        mm16r<1280>(sm, wQ, wave, lane, a0, a1);
#pragma unroll
        for (int i = 0; i < 4; ++i) {
          psum[wave][rb + i][cc] = a0[i];
          psum[wave][16 + rb + i][cc] = a1[i];
        }
        __syncthreads();
        float2 s0 = *(const float2*)&psum[0][m][jc];
        float2 s1v = *(const float2*)&psum[1][m][jc];
        float2 s2v = *(const float2*)&psum[2][m][jc];
        float2 s3v = *(const float2*)&psum[3][m][jc];
        float v0 = s0.x + s1v.x + s2v.x + s3v.x + p.bh0[2 * HD + j0];
        float v1 = s0.y + s1v.y + s2v.y + s3v.y + p.bh0[2 * HD + j0 + 1];
        float g0 = tanhf(v0), g1 = tanhf(v1);
        float hn0 = zc0 * hpc.x + (1.f - zc0) * g0;
        float hn1 = zc1 * hpc.y + (1.f - zc1) * g1;
        cst8(p.h0f32 + (size_t)(t & 1) * MBHD + m * HD + j0, pk64(hn0, hn1));
        cst4(p.h016 + (size_t)(t & 1) * MBHD + m * HD + j0, pk16x2(hn0, hn1));
      }
    } else if (w < 80) {
      if (t >= 2) {
        int j0 = ((w - 64) << 4) + jc;
        stage16<1024, 0>(sm, p.h116 + (size_t)(t & 1) * MBHD, tid);
        __syncthreads();
        f32x4 a0, a1;
        mm16r<1024>(sm, wQ, wave, lane, a0, a1);
#pragma unroll
        for (int i = 0; i < 4; ++i) {
          psum[wave][rb + i][cc] = a0[i];
          psum[wave][16 + rb + i][cc] = a1[i];
        }
        __syncthreads();
        float2 s0 = *(const float2*)&psum[0][m][jc];
        float2 s1v = *(const float2*)&psum[1][m][jc];
        float2 s2v = *(const float2*)&psum[2][m][jc];
        float2 s3v = *(const float2*)&psum[3][m][jc];
        float v0 = s0.x + s1v.x + s2v.x + s3v.x + p.by[j0];
        float v1 = s0.y + s1v.y + s2v.y + s3v.y + p.by[j0 + 1];
        *(float2*)&p.out[((size_t)m * SEQ + (t - 2)) * OD + j0] = make_float2(v0, v1);
      }
    } else if (w >= 128 && w < 192) {
      if (t >= 1 && t <= SEQ) {
        int j0 = ((w - 128) << 4) + jc;
        // h0(t-1) chunks [0,128) persist in LDS from this block's alpha.
        stage16<2048, 128>(sm, p.rh116, tid);
        __syncthreads();
        f32x4 a0, a1;
        mm16r<2048>(sm, wQ, wave, lane, a0, a1);
#pragma unroll
        for (int i = 0; i < 4; ++i) {
          psum[wave][rb + i][cc] = a0[i];
          psum[wave][16 + rb + i][cc] = a1[i];
        }
        __syncthreads();
        float2 s0 = *(const float2*)&psum[0][m][jc];
        float2 s1v = *(const float2*)&psum[1][m][jc];
        float2 s2v = *(const float2*)&psum[2][m][jc];
        float2 s3v = *(const float2*)&psum[3][m][jc];
        float v0 = s0.x + s1v.x + s2v.x + s3v.x + p.bh1[2 * HD + j0];
        float v1 = s0.y + s1v.y + s2v.y + s3v.y + p.bh1[2 * HD + j0 + 1];
        float g0 = tanhf(v0), g1 = tanhf(v1);
        float hn0 = zc0 * hpc.x + (1.f - zc0) * g0;
        float hn1 = zc1 * hpc.y + (1.f - zc1) * g1;
        cst8(p.h1f32 + (size_t)((t - 1) & 1) * MBHD + m * HD + j0, pk64(hn0, hn1));
        cst4(p.h116 + (size_t)((t - 1) & 1) * MBHD + m * HD + j0, pk16x2(hn0, hn1));
      }
    }
    gbar(p.bar, w, 2u * t + 1u);
  }
  // Epilogue: final hidden states (both in parity buffer 1 after step 511).
  if (w < MB) {
    const float* h0f = p.h0f32 + MBHD;
    const float* h1f = p.h1f32 + MBHD;
#pragma unroll
    for (int it = 0; it < 4; ++it) {
      int i2 = (it * 256 + tid) * 2;  // 0..2046 step 2 over 2*HD
      float2 v = (i2 < HD) ? upk64(cld8(&h0f[w * HD + i2]))
                           : upk64(cld8(&h1f[w * HD + (i2 - HD)]));
      *(float2*)&p.out[(size_t)MB * SEQ * OD + (size_t)w * 2 * HD + i2] = v;
    }
  }
}

// ---------------- prologue kernels ----------------

__global__ void convx_k(const float* __restrict__ x, u16* __restrict__ X16) {
  size_t i = (size_t)blockIdx.x * 256 + threadIdx.x;
  const float4* s = (const float4*)x + i * 2;
  float4 a = s[0], b = s[1];
  u16 o[8];
  o[0] = f16b(a.x); o[1] = f16b(a.y); o[2] = f16b(a.z); o[3] = f16b(a.w);
  o[4] = f16b(b.x); o[5] = f16b(b.y); o[6] = f16b(b.z); o[7] = f16b(b.w);
  *(int4*)(X16 + i * 8) = *(const int4*)o;
}

__global__ void inith_k(const float* __restrict__ h0in,
                        float* h0f32, float* h1f32, u16* h016, u16* h116) {
  int idx = blockIdx.x * 256 + threadIdx.x;  // [b][l][h], 65536
  float v = h0in[idx];
  int b = idx >> 11, rem = idx & 2047;
  int l = rem >> 10, h = rem & 1023;
  int o = MBHD + b * HD + h;                 // parity buffer 1
  if (l == 0) { h0f32[o] = v; h016[o] = f16b(v); }
  else        { h1f32[o] = v; h116[o] = f16b(v); }
}

// Build [N][K] fp16 transposed weight blocks (K = concat Wx rows then Wh rows).
__global__ void wtrans_k(const float* __restrict__ Wx0, const float* __restrict__ Wh0,
                         const float* __restrict__ Wx1, const float* __restrict__ Wh1,
                         const float* __restrict__ Wy,
                         u16* A0, u16* B0, u16* C1, u16* D1, u16* Y) {
  __shared__ u16 tile[32][34];
  int mid = blockIdx.z;
  int K, N, k1, coloff, ld; const float *b1, *b2; u16* dst;
  if (mid == 0)      { K = 1280; N = 2048; k1 = ID; coloff = 0;    ld = 3072; b1 = Wx0; b2 = Wh0; dst = A0; }
  else if (mid == 1) { K = 1280; N = 1024; k1 = ID; coloff = 2048; ld = 3072; b1 = Wx0; b2 = Wh0; dst = B0; }
  else if (mid == 2) { K = 2048; N = 2048; k1 = HD; coloff = 0;    ld = 3072; b1 = Wx1; b2 = Wh1; dst = C1; }
  else if (mid == 3) { K = 2048; N = 1024; k1 = HD; coloff = 2048; ld = 3072; b1 = Wx1; b2 = Wh1; dst = D1; }
  else               { K = 1024; N = 256;  k1 = HD; coloff = 0;    ld = OD;   b1 = Wy;  b2 = Wy;  dst = Y;  }
  int k0 = blockIdx.x << 5, n0 = blockIdx.y << 5;
  if (k0 >= K || n0 >= N) return;
  int tx = threadIdx.x & 31, ty = threadIdx.x >> 5;
#pragma unroll
  for (int i = 0; i < 4; ++i) {
    int kk = (ty << 2) + i, k = k0 + kk;
    int col = coloff + n0 + tx;
    const float* src = (k < k1) ? (b1 + (size_t)k * ld + col)
                                : (b2 + (size_t)(k - k1) * ld + col);
    tile[kk][tx] = f16b(*src);
  }
  __syncthreads();
#pragma unroll
  for (int i = 0; i < 4; ++i) {
    int nn = (ty << 2) + i;
    dst[(size_t)(n0 + nn) * K + k0 + tx] = tile[tx][nn];
  }
}

// ---------------- host launch ----------------

extern "C" void kernel_launch(void* const* d_in, const int* in_sizes, int n_in,
                              void* d_out, int out_size, void* d_ws, size_t ws_size,
                              hipStream_t stream) {
  const float* x    = (const float*)d_in[0];
  const float* h0in = (const float*)d_in[1];
  const float* Wx0  = (const float*)d_in[2];
  const float* Wh0  = (const float*)d_in[3];
  const float* bh0  = (const float*)d_in[4];
  const float* Wx1  = (const float*)d_in[5];
  const float* Wh1  = (const float*)d_in[6];
  const float* bh1  = (const float*)d_in[7];
  const float* Wy   = (const float*)d_in[8];
  const float* by   = (const float*)d_in[9];

  char* ws = (char*)d_ws;
  size_t off = 0;
  auto alloc = [&](size_t bytes) {
    void* pp = ws + off;
    off += (bytes + 255) & ~(size_t)255;
    return pp;
  };
  u16* WtA0 = (u16*)alloc(2048ull * 1280 * 2);
  u16* WtB0 = (u16*)alloc(1024ull * 1280 * 2);
  u16* WtC1 = (u16*)alloc(2048ull * 2048 * 2);
  u16* WtD1 = (u16*)alloc(1024ull * 2048 * 2);
  u16* WtY  = (u16*)alloc(256ull * 1024 * 2);
  u16* X16  = (u16*)alloc((size_t)MB * SEQ * ID * 2);
  u16* h016  = (u16*)alloc(2ull * MBHD * 2);
  u16* h116  = (u16*)alloc(2ull * MBHD * 2);
  u16* rh016 = (u16*)alloc((size_t)MBHD * 2);
  u16* rh116 = (u16*)alloc((size_t)MBHD * 2);
  float* h0f32 = (float*)alloc(2ull * MBHD * 4);
  float* h1f32 = (float*)alloc(2ull * MBHD * 4);
  unsigned* bar = (unsigned*)alloc(8192);

  hipMemsetAsync(bar, 0, 8192, stream);
  hipLaunchKernelGGL(convx_k, dim3((MB * SEQ * ID / 8) / 256), dim3(256), 0, stream,
                     x, X16);
  hipLaunchKernelGGL(wtrans_k, dim3(64, 64, 5), dim3(256), 0, stream,
                     Wx0, Wh0, Wx1, Wh1, Wy, WtA0, WtB0, WtC1, WtD1, WtY);
  hipLaunchKernelGGL(inith_k, dim3(65536 / 256), dim3(256), 0, stream,
                     h0in, h0f32, h1f32, h016, h116);

  GruP p;
  p.bh0 = bh0; p.bh1 = bh1; p.by = by;
  p.X16 = X16; p.WtA0 = WtA0; p.WtB0 = WtB0; p.WtC1 = WtC1; p.WtD1 = WtD1; p.WtY = WtY;
  p.h016 = h016; p.h116 = h116; p.rh016 = rh016; p.rh116 = rh116;
  p.h0f32 = h0f32; p.h1f32 = h1f32;
  p.bar = bar;
  p.out = (float*)d_out;

  hipLaunchKernelGGL(gru_main, dim3(NBLK), dim3(256), 0, stream, p);
}